// Round 1
// baseline (1326.378 us; speedup 1.0000x reference)
//
#include <hip/hip_runtime.h>

typedef __bf16 bf16;
typedef __bf16 bf16x8 __attribute__((ext_vector_type(8)));
typedef float f32x4 __attribute__((ext_vector_type(4)));

#define S 2048
#define DM 2048
#define HD 128
#define H 16
#define NQKV 3072
#define N_ITER_DEV 32

// ---------------- fp32 -> bf16 convert ----------------
__global__ void cvt_kernel(const float* __restrict__ in, bf16* __restrict__ out, int n) {
    int i = blockIdx.x * blockDim.x + threadIdx.x;
    if (i < n) out[i] = (bf16)in[i];
}

// ---------------- GEMM: C[m][n] = sum_k A[m][k]*B[n][k]  (A MxK, B NxK, both bf16; C fp32 MxN)
__global__ void gemm_bt_kernel(const bf16* __restrict__ A, const bf16* __restrict__ B,
                               float* __restrict__ C, int Ndim, int K) {
    int m0 = blockIdx.x * 16, n0 = blockIdx.y * 16;
    int l = threadIdx.x;
    int lane16 = l & 15, quad = l >> 4;
    const bf16* ap = A + (size_t)(m0 + lane16) * K + quad * 8;
    const bf16* bp = B + (size_t)(n0 + lane16) * K + quad * 8;
    f32x4 acc = {0.f, 0.f, 0.f, 0.f};
    for (int kk = 0; kk < K; kk += 32) {
        bf16x8 a = *(const bf16x8*)(ap + kk);
        bf16x8 b = *(const bf16x8*)(bp + kk);
        acc = __builtin_amdgcn_mfma_f32_16x16x32_bf16(a, b, acc, 0, 0, 0);
    }
    float* cp = C + (size_t)(m0 + quad * 4) * Ndim + n0 + lane16;
#pragma unroll
    for (int r = 0; r < 4; r++) cp[(size_t)r * Ndim] = acc[r];
}

// ---------------- RoPE + reorder + scale-fold + bf16 ----------------
// qkv_raw: [S][3072] fp32 (q 0..2047 | k 2048..2559 | v 2560..3071)
// qs: [H][S][HD] bf16 (rope, * scaling*(alpha-1));  kb: [4][S][HD] bf16 (rope);  vT: [4][HD][S] bf16
__global__ void rope_kernel(const float* __restrict__ qkv, const float* __restrict__ cosb,
                            const float* __restrict__ sinb, bf16* __restrict__ qs,
                            bf16* __restrict__ kb, bf16* __restrict__ vT) {
    int col = blockIdx.x * 256 + threadIdx.x;  // 0..3071
    int s = blockIdx.y;
    const float* row = qkv + (size_t)s * NQKV;
    float v = row[col];
    if (col < DM) {
        int h = col >> 7, d = col & 127;
        float c = cosb[s * HD + d], sn = sinb[s * HD + d];
        float other = row[(h << 7) + ((d < 64) ? (d + 64) : (d - 64))];
        float rot = (d < 64) ? -other : other;
        float o = v * c + rot * sn;
        qs[((size_t)h * S + s) * HD + d] = (bf16)(o * 0.04419417382415922f);  // HD^-0.5 * 0.5
    } else if (col < DM + 512) {
        int c2 = col - DM;
        int kv = c2 >> 7, d = c2 & 127;
        float c = cosb[s * HD + d], sn = sinb[s * HD + d];
        float other = row[DM + (kv << 7) + ((d < 64) ? (d + 64) : (d - 64))];
        float rot = (d < 64) ? -other : other;
        float o = v * c + rot * sn;
        kb[((size_t)kv * S + s) * HD + d] = (bf16)o;
    } else {
        int c2 = col - DM - 512;
        int kv = c2 >> 7, d = c2 & 127;
        vT[((size_t)kv * HD + d) * S + s] = (bf16)v;
    }
}

// ---------------- fused scores + causal mask + entmax(alpha=1.5) bisection + attn write ----------------
// Block: 1024 threads = 16 waves; handles (head, 16 query rows). Wave w owns row r0+w.
// Scores X = qs . k computed by MFMA into LDS in 512-col segments, then pulled into
// 32 regs/lane (row layout) for register-resident bisection.
template <int SEGS>
__global__ __launch_bounds__(1024) void attn_kernel(const bf16* __restrict__ qs,
                                                    const bf16* __restrict__ kb,
                                                    float* __restrict__ attn, int bx_base) {
    constexpr int NREG = SEGS * 8;
    __shared__ float sc[16][528];  // 512 + 16 pad
    int bx = bx_base + blockIdx.x;
    int h = blockIdx.y;
    int r0 = bx * 16;
    int jlen = r0 + 16;  // valid columns < jlen
    int l = threadIdx.x & 63;
    int w = threadIdx.x >> 6;
    int lane16 = l & 15, quad = l >> 4;

    // A fragments (16 rows x K=128) — every wave keeps its own copy
    const bf16* qrow = qs + ((size_t)h * S + (r0 + lane16)) * HD + quad * 8;
    bf16x8 afrag[4];
#pragma unroll
    for (int kc = 0; kc < 4; kc++) afrag[kc] = *(const bf16x8*)(qrow + kc * 32);

    const bf16* kbase = kb + (size_t)(h >> 2) * S * HD;
    float xr[NREG];
    int my_i = r0 + w;

#pragma unroll
    for (int sgi = 0; sgi < SEGS; sgi++) {
        int j0 = sgi * 512;
        // each wave computes 2 of the 32 16-col tiles in this segment
#pragma unroll
        for (int tt = 0; tt < 2; tt++) {
            int t = w + tt * 16;
            int jt = j0 + t * 16;
            if (jt < jlen) {
                f32x4 acc = {0.f, 0.f, 0.f, 0.f};
                const bf16* kp = kbase + (size_t)(jt + lane16) * HD + quad * 8;
#pragma unroll
                for (int kc = 0; kc < 4; kc++) {
                    bf16x8 b = *(const bf16x8*)(kp + kc * 32);
                    acc = __builtin_amdgcn_mfma_f32_16x16x32_bf16(afrag[kc], b, acc, 0, 0, 0);
                }
                int jj = jt + lane16;
#pragma unroll
                for (int r = 0; r < 4; r++) {
                    int rowi = quad * 4 + r;
                    float v = acc[r];
                    if (jj > r0 + rowi) v = -1e30f;  // causal mask
                    sc[rowi][t * 16 + lane16] = v;
                }
            }
        }
        __syncthreads();
        // wave w pulls its row into registers
#pragma unroll
        for (int c = 0; c < 8; c++) {
            int j = j0 + c * 64 + l;
            xr[sgi * 8 + c] = (j < jlen) ? sc[w][c * 64 + l] : -1e30f;
        }
        __syncthreads();
    }

    // row max (butterfly over 64 lanes)
    float m = -1e30f;
#pragma unroll
    for (int c = 0; c < NREG; c++) m = fmaxf(m, xr[c]);
#pragma unroll
    for (int off = 1; off < 64; off <<= 1) m = fmaxf(m, __shfl_xor(m, off));

    float tau_lo = m - 1.0f;
    float dm = 0.97790291309f;  // 1 - (1/2048)^0.5
    float tau_m = tau_lo;
    for (int it = 0; it < N_ITER_DEV; it++) {
        dm *= 0.5f;
        tau_m = tau_lo + dm;
        float f = 0.f;
#pragma unroll
        for (int c = 0; c < NREG; c++) {
            float t = fmaxf(xr[c] - tau_m, 0.f);
            f = fmaf(t, t, f);
        }
#pragma unroll
        for (int off = 1; off < 64; off <<= 1) f += __shfl_xor(f, off);
        tau_lo = (f >= 1.0f) ? tau_m : tau_lo;
    }

    float ssum = 0.f;
#pragma unroll
    for (int c = 0; c < NREG; c++) {
        float t = fmaxf(xr[c] - tau_m, 0.f);
        ssum = fmaf(t, t, ssum);
    }
#pragma unroll
    for (int off = 1; off < 64; off <<= 1) ssum += __shfl_xor(ssum, off);
    float inv = 1.0f / ssum;

    float* arow = attn + ((size_t)h * S + my_i) * S;
#pragma unroll
    for (int c = 0; c < NREG; c++) {
        float t = fmaxf(xr[c] - tau_m, 0.f);
        arow[c * 64 + l] = t * t * inv;
    }
    for (int j = SEGS * 512 + l; j < S; j += 64) arow[j] = 0.f;  // upper-triangle zeros
}

// ---------------- out_h = attn @ v  -> o[s][h*HD+d] bf16 ----------------
__global__ void av_kernel(const float* __restrict__ attn, const bf16* __restrict__ vT,
                          bf16* __restrict__ o) {
    int m0 = blockIdx.x * 16;
    int d0 = blockIdx.y * 16;
    int h = blockIdx.z;
    int l = threadIdx.x;
    int lane16 = l & 15, quad = l >> 4;
    const float* ap = attn + ((size_t)h * S + m0 + lane16) * S + quad * 8;
    const bf16* bp = vT + ((size_t)(h >> 2) * HD + d0 + lane16) * S + quad * 8;
    int ktiles = m0 / 32 + 1;  // attn is zero beyond the diagonal, rounded to 32
    f32x4 acc = {0.f, 0.f, 0.f, 0.f};
    for (int kt = 0; kt < ktiles; kt++) {
        float4 f0 = *(const float4*)(ap + kt * 32);
        float4 f1 = *(const float4*)(ap + kt * 32 + 4);
        bf16x8 a;
        a[0] = (bf16)f0.x; a[1] = (bf16)f0.y; a[2] = (bf16)f0.z; a[3] = (bf16)f0.w;
        a[4] = (bf16)f1.x; a[5] = (bf16)f1.y; a[6] = (bf16)f1.z; a[7] = (bf16)f1.w;
        bf16x8 b = *(const bf16x8*)(bp + kt * 32);
        acc = __builtin_amdgcn_mfma_f32_16x16x32_bf16(a, b, acc, 0, 0, 0);
    }
    bf16* op = o + (size_t)(m0 + quad * 4) * DM + h * HD + d0 + lane16;
#pragma unroll
    for (int r = 0; r < 4; r++) op[(size_t)r * DM] = (bf16)acc[r];
}

extern "C" void kernel_launch(void* const* d_in, const int* in_sizes, int n_in,
                              void* d_out, int out_size, void* d_ws, size_t ws_size,
                              hipStream_t stream) {
    const float* hidden = (const float*)d_in[0];
    const float* cosb   = (const float*)d_in[1];
    const float* sinb   = (const float*)d_in[2];
    const float* wq     = (const float*)d_in[3];
    const float* wk     = (const float*)d_in[4];
    const float* wv     = (const float*)d_in[5];
    const float* wo     = (const float*)d_in[6];
    char* ws = (char*)d_ws;
    // workspace map (64 MB total)
    bf16*  bf_hidden = (bf16*)(ws);                    // 8 MB; reused as o_bf16 after QKV GEMM
    bf16*  bf_wqkv   = (bf16*)(ws + 8388608);          // 12 MB (wq|wk|wv rows)
    bf16*  bf_wo     = (bf16*)(ws + 20971520);         // 8 MB
    float* qkv_raw   = (float*)(ws + 29360128);        // 24 MB
    bf16*  qsb       = (bf16*)(ws + 54525952);         // 8 MB  [H][S][HD]
    bf16*  kbb       = (bf16*)(ws + 62914560);         // 2 MB  [4][S][HD]
    bf16*  vTb       = (bf16*)(ws + 65011712);         // 2 MB  [4][HD][S]
    float* out  = (float*)d_out;
    float* attn = out + 4194304;

    cvt_kernel<<<dim3(16384), 256, 0, stream>>>(hidden, bf_hidden, 2048 * 2048);
    cvt_kernel<<<dim3(16384), 256, 0, stream>>>(wq, bf_wqkv, 2048 * 2048);
    cvt_kernel<<<dim3(4096), 256, 0, stream>>>(wk, bf_wqkv + 2048 * 2048, 512 * 2048);
    cvt_kernel<<<dim3(4096), 256, 0, stream>>>(wv, bf_wqkv + 2048 * 2048 + 512 * 2048, 512 * 2048);
    cvt_kernel<<<dim3(16384), 256, 0, stream>>>(wo, bf_wo, 2048 * 2048);

    // QKV projection: [2048 x 2048] @ [3072 x 2048]^T
    gemm_bt_kernel<<<dim3(128, 192), 64, 0, stream>>>(bf_hidden, bf_wqkv, qkv_raw, NQKV, DM);

    rope_kernel<<<dim3(12, S), 256, 0, stream>>>(qkv_raw, cosb, sinb, qsb, kbb, vTb);

    // fused scores + entmax, templated on causal length (SEGS*512 columns)
    attn_kernel<1><<<dim3(32, H), 1024, 0, stream>>>(qsb, kbb, attn, 0);
    attn_kernel<2><<<dim3(32, H), 1024, 0, stream>>>(qsb, kbb, attn, 32);
    attn_kernel<3><<<dim3(32, H), 1024, 0, stream>>>(qsb, kbb, attn, 64);
    attn_kernel<4><<<dim3(32, H), 1024, 0, stream>>>(qsb, kbb, attn, 96);

    // attn @ v  -> o (bf16, [s][h*HD+d]), reusing hidden_bf16 region
    av_kernel<<<dim3(128, 8, H), 64, 0, stream>>>(attn, vTb, bf_hidden);

    // out = o @ wo^T  (fp32 to d_out[0:4194304))
    gemm_bt_kernel<<<dim3(128, 128), 64, 0, stream>>>(bf_hidden, bf_wo, out, DM, DM);
}

// Round 2
// 693.932 us; speedup vs baseline: 1.9114x; 1.9114x over previous
//
#include <hip/hip_runtime.h>

typedef __bf16 bf16;
typedef __bf16 bf16x4 __attribute__((ext_vector_type(4)));
typedef __bf16 bf16x8 __attribute__((ext_vector_type(8)));
typedef float f32x4 __attribute__((ext_vector_type(4)));

#define S 2048
#define DM 2048
#define HD 128
#define H 16
#define NQKV 3072
#define N_ITER_DEV 32

__device__ __forceinline__ void gl2lds16(const void* g, void* l) {
    __builtin_amdgcn_global_load_lds(
        (const __attribute__((address_space(1))) void*)g,
        (__attribute__((address_space(3))) void*)l, 16, 0, 0);
}

// ---------------- fp32 -> bf16 convert (vectorized x4) ----------------
__global__ void cvt4_kernel(const float* __restrict__ in, bf16* __restrict__ out, int n4) {
    int i = blockIdx.x * blockDim.x + threadIdx.x;
    if (i < n4) {
        float4 f = ((const float4*)in)[i];
        bf16x4 o;
        o[0] = (bf16)f.x; o[1] = (bf16)f.y; o[2] = (bf16)f.z; o[3] = (bf16)f.w;
        ((bf16x4*)out)[i] = o;
    }
}

// ---------------- 128x128-tile GEMM: C[m][n] = sum_k A[m][k]*B[n][k] ----------------
// A: MxK bf16 row-major, B: NxK bf16 row-major, C: MxN fp32. 256 thr = 4 waves,
// each wave computes a 64x64 quadrant (4x4 of 16x16x32 MFMA). BK=32.
// Staging via global_load_lds width=16 (wave-uniform LDS base + lane*16).
__global__ __launch_bounds__(256) void gemm128_bt(const bf16* __restrict__ A,
                                                  const bf16* __restrict__ B,
                                                  float* __restrict__ C, int Ndim, int K) {
    __shared__ bf16 As[128 * 32];  // 8 KB, row-major [row][32]
    __shared__ bf16 Bs[128 * 32];  // 8 KB
    int m0 = blockIdx.x * 128, n0 = blockIdx.y * 128;
    int t = threadIdx.x;
    int l = t & 63, w = t >> 6;
    int lane16 = l & 15, quad = l >> 4;

    // staging chunk ids (16B chunks; chunk c covers row c>>2, cols (c&3)*8..+7)
    int c0 = (w * 2) * 64 + l;
    int c1 = c0 + 64;
    const bf16* Abase = A + (size_t)m0 * K;
    const bf16* Bbase = B + (size_t)n0 * K;

    int wm = (w & 1) * 64, wn = (w >> 1) * 64;
    f32x4 acc[4][4];
#pragma unroll
    for (int i = 0; i < 4; i++)
#pragma unroll
        for (int j = 0; j < 4; j++) acc[i][j] = (f32x4){0.f, 0.f, 0.f, 0.f};

    for (int k0 = 0; k0 < K; k0 += 32) {
        gl2lds16(Abase + (size_t)(c0 >> 2) * K + k0 + (c0 & 3) * 8, &As[(w * 2) * 512]);
        gl2lds16(Abase + (size_t)(c1 >> 2) * K + k0 + (c1 & 3) * 8, &As[(w * 2 + 1) * 512]);
        gl2lds16(Bbase + (size_t)(c0 >> 2) * K + k0 + (c0 & 3) * 8, &Bs[(w * 2) * 512]);
        gl2lds16(Bbase + (size_t)(c1 >> 2) * K + k0 + (c1 & 3) * 8, &Bs[(w * 2 + 1) * 512]);
        __syncthreads();
        bf16x8 af[4], bfr[4];
#pragma unroll
        for (int i = 0; i < 4; i++)
            af[i] = *(const bf16x8*)&As[(wm + i * 16 + lane16) * 32 + quad * 8];
#pragma unroll
        for (int j = 0; j < 4; j++)
            bfr[j] = *(const bf16x8*)&Bs[(wn + j * 16 + lane16) * 32 + quad * 8];
#pragma unroll
        for (int i = 0; i < 4; i++)
#pragma unroll
            for (int j = 0; j < 4; j++)
                acc[i][j] = __builtin_amdgcn_mfma_f32_16x16x32_bf16(af[i], bfr[j], acc[i][j], 0, 0, 0);
        __syncthreads();
    }
#pragma unroll
    for (int i = 0; i < 4; i++)
#pragma unroll
        for (int j = 0; j < 4; j++) {
            float* cp = C + (size_t)(m0 + wm + i * 16 + quad * 4) * Ndim + n0 + wn + j * 16 + lane16;
#pragma unroll
            for (int r = 0; r < 4; r++) cp[(size_t)r * Ndim] = acc[i][j][r];
        }
}

// ---------------- RoPE + reorder + scale-fold + bf16 ----------------
__global__ void rope_kernel(const float* __restrict__ qkv, const float* __restrict__ cosb,
                            const float* __restrict__ sinb, bf16* __restrict__ qs,
                            bf16* __restrict__ kb, bf16* __restrict__ vT) {
    int col = blockIdx.x * 256 + threadIdx.x;  // 0..3071
    int s = blockIdx.y;
    const float* row = qkv + (size_t)s * NQKV;
    float v = row[col];
    if (col < DM) {
        int h = col >> 7, d = col & 127;
        float c = cosb[s * HD + d], sn = sinb[s * HD + d];
        float other = row[(h << 7) + ((d < 64) ? (d + 64) : (d - 64))];
        float rot = (d < 64) ? -other : other;
        float o = v * c + rot * sn;
        qs[((size_t)h * S + s) * HD + d] = (bf16)(o * 0.04419417382415922f);  // HD^-0.5 * (alpha-1)
    } else if (col < DM + 512) {
        int c2 = col - DM;
        int kv = c2 >> 7, d = c2 & 127;
        float c = cosb[s * HD + d], sn = sinb[s * HD + d];
        float other = row[DM + (kv << 7) + ((d < 64) ? (d + 64) : (d - 64))];
        float rot = (d < 64) ? -other : other;
        float o = v * c + rot * sn;
        kb[((size_t)kv * S + s) * HD + d] = (bf16)o;
    } else {
        int c2 = col - DM - 512;
        int kv = c2 >> 7, d = c2 & 127;
        vT[((size_t)kv * HD + d) * S + s] = (bf16)v;
    }
}

// ---------------- fused scores + causal mask + entmax(1.5) bisection + attn write ----------------
template <int SEGS>
__global__ __launch_bounds__(1024) void attn_kernel(const bf16* __restrict__ qs,
                                                    const bf16* __restrict__ kb,
                                                    float* __restrict__ attn, int bx_base) {
    constexpr int NREG = SEGS * 8;
    __shared__ float sc[16][528];
    int bx = bx_base + blockIdx.x;
    int h = blockIdx.y;
    int r0 = bx * 16;
    int jlen = r0 + 16;
    int l = threadIdx.x & 63;
    int w = threadIdx.x >> 6;
    int lane16 = l & 15, quad = l >> 4;

    const bf16* qrow = qs + ((size_t)h * S + (r0 + lane16)) * HD + quad * 8;
    bf16x8 afrag[4];
#pragma unroll
    for (int kc = 0; kc < 4; kc++) afrag[kc] = *(const bf16x8*)(qrow + kc * 32);

    const bf16* kbase = kb + (size_t)(h >> 2) * S * HD;
    float xr[NREG];
    int my_i = r0 + w;

#pragma unroll
    for (int sgi = 0; sgi < SEGS; sgi++) {
        int j0 = sgi * 512;
#pragma unroll
        for (int tt = 0; tt < 2; tt++) {
            int t = w + tt * 16;
            int jt = j0 + t * 16;
            if (jt < jlen) {
                f32x4 acc = {0.f, 0.f, 0.f, 0.f};
                const bf16* kp = kbase + (size_t)(jt + lane16) * HD + quad * 8;
#pragma unroll
                for (int kc = 0; kc < 4; kc++) {
                    bf16x8 b = *(const bf16x8*)(kp + kc * 32);
                    acc = __builtin_amdgcn_mfma_f32_16x16x32_bf16(afrag[kc], b, acc, 0, 0, 0);
                }
                int jj = jt + lane16;
#pragma unroll
                for (int r = 0; r < 4; r++) {
                    int rowi = quad * 4 + r;
                    float v = acc[r];
                    if (jj > r0 + rowi) v = -1e30f;
                    sc[rowi][t * 16 + lane16] = v;
                }
            }
        }
        __syncthreads();
#pragma unroll
        for (int c = 0; c < 8; c++) {
            int j = j0 + c * 64 + l;
            xr[sgi * 8 + c] = (j < jlen) ? sc[w][c * 64 + l] : -1e30f;
        }
        __syncthreads();
    }

    float m = -1e30f;
#pragma unroll
    for (int c = 0; c < NREG; c++) m = fmaxf(m, xr[c]);
#pragma unroll
    for (int off = 1; off < 64; off <<= 1) m = fmaxf(m, __shfl_xor(m, off));

    float tau_lo = m - 1.0f;
    float dm = 0.97790291309f;  // 1 - (1/2048)^0.5
    float tau_m = tau_lo;
    for (int it = 0; it < N_ITER_DEV; it++) {
        dm *= 0.5f;
        tau_m = tau_lo + dm;
        float f = 0.f;
#pragma unroll
        for (int c = 0; c < NREG; c++) {
            float t = fmaxf(xr[c] - tau_m, 0.f);
            f = fmaf(t, t, f);
        }
#pragma unroll
        for (int off = 1; off < 64; off <<= 1) f += __shfl_xor(f, off);
        tau_lo = (f >= 1.0f) ? tau_m : tau_lo;
    }

    float ssum = 0.f;
#pragma unroll
    for (int c = 0; c < NREG; c++) {
        float t = fmaxf(xr[c] - tau_m, 0.f);
        ssum = fmaf(t, t, ssum);
    }
#pragma unroll
    for (int off = 1; off < 64; off <<= 1) ssum += __shfl_xor(ssum, off);
    float inv = 1.0f / ssum;

    float* arow = attn + ((size_t)h * S + my_i) * S;
#pragma unroll
    for (int c = 0; c < NREG; c++) {
        float t = fmaxf(xr[c] - tau_m, 0.f);
        arow[c * 64 + l] = t * t * inv;
    }
    for (int j = SEGS * 512 + l; j < S; j += 64) arow[j] = 0.f;
}

// ---------------- o[s][h*HD+d] = attn @ v, 64x128-tile, LDS-staged ----------------
// attn fp32 staged->bf16 in LDS (read once per block); vT bf16 via global_load_lds.
__global__ __launch_bounds__(256) void av128(const float* __restrict__ attn,
                                             const bf16* __restrict__ vT,
                                             bf16* __restrict__ o) {
    __shared__ bf16 As[64 * 32];   // 4 KB
    __shared__ bf16 Bs[128 * 32];  // 8 KB
    int m0 = blockIdx.x * 64;
    int h = blockIdx.y;
    int t = threadIdx.x, l = t & 63, w = t >> 6;
    int lane16 = l & 15, quad = l >> 4;
    const float* Abase = attn + ((size_t)h * S + m0) * S;
    const bf16* Bbase = vT + (size_t)(h >> 2) * HD * S;
    int wm = (w & 1) * 32, wn = (w >> 1) * 64;
    f32x4 acc[2][4];
#pragma unroll
    for (int i = 0; i < 2; i++)
#pragma unroll
        for (int j = 0; j < 4; j++) acc[i][j] = (f32x4){0.f, 0.f, 0.f, 0.f};

    int ar = t >> 2, ac = (t & 3) * 8;  // A staging: one 16B (8-elem) chunk per thread
    int cB0 = (w * 2) * 64 + l, cB1 = cB0 + 64;
    int Kv = m0 + 64;  // causal: attn is exactly zero beyond this (rows < m0+64)

    for (int k0 = 0; k0 < Kv; k0 += 32) {
        float4 f0 = *(const float4*)(Abase + (size_t)ar * S + k0 + ac);
        float4 f1 = *(const float4*)(Abase + (size_t)ar * S + k0 + ac + 4);
        bf16x8 a8;
        a8[0] = (bf16)f0.x; a8[1] = (bf16)f0.y; a8[2] = (bf16)f0.z; a8[3] = (bf16)f0.w;
        a8[4] = (bf16)f1.x; a8[5] = (bf16)f1.y; a8[6] = (bf16)f1.z; a8[7] = (bf16)f1.w;
        *(bf16x8*)&As[ar * 32 + ac] = a8;
        gl2lds16(Bbase + (size_t)(cB0 >> 2) * S + k0 + (cB0 & 3) * 8, &Bs[(w * 2) * 512]);
        gl2lds16(Bbase + (size_t)(cB1 >> 2) * S + k0 + (cB1 & 3) * 8, &Bs[(w * 2 + 1) * 512]);
        __syncthreads();
        bf16x8 af[2], bfr[4];
#pragma unroll
        for (int i = 0; i < 2; i++)
            af[i] = *(const bf16x8*)&As[(wm + i * 16 + lane16) * 32 + quad * 8];
#pragma unroll
        for (int j = 0; j < 4; j++)
            bfr[j] = *(const bf16x8*)&Bs[(wn + j * 16 + lane16) * 32 + quad * 8];
#pragma unroll
        for (int i = 0; i < 2; i++)
#pragma unroll
            for (int j = 0; j < 4; j++)
                acc[i][j] = __builtin_amdgcn_mfma_f32_16x16x32_bf16(af[i], bfr[j], acc[i][j], 0, 0, 0);
        __syncthreads();
    }
#pragma unroll
    for (int i = 0; i < 2; i++)
#pragma unroll
        for (int j = 0; j < 4; j++) {
            bf16* op = o + (size_t)(m0 + wm + i * 16 + quad * 4) * DM + h * HD + wn + j * 16 + lane16;
#pragma unroll
            for (int r = 0; r < 4; r++) op[(size_t)r * DM] = (bf16)acc[i][j][r];
        }
}

extern "C" void kernel_launch(void* const* d_in, const int* in_sizes, int n_in,
                              void* d_out, int out_size, void* d_ws, size_t ws_size,
                              hipStream_t stream) {
    const float* hidden = (const float*)d_in[0];
    const float* cosb   = (const float*)d_in[1];
    const float* sinb   = (const float*)d_in[2];
    const float* wq     = (const float*)d_in[3];
    const float* wk     = (const float*)d_in[4];
    const float* wv     = (const float*)d_in[5];
    const float* wo     = (const float*)d_in[6];
    char* ws = (char*)d_ws;
    bf16*  bf_hidden = (bf16*)(ws);                    // 8 MB; reused as o_bf16 later
    bf16*  bf_wqkv   = (bf16*)(ws + 8388608);          // 12 MB
    bf16*  bf_wo     = (bf16*)(ws + 20971520);         // 8 MB
    float* qkv_raw   = (float*)(ws + 29360128);        // 24 MB
    bf16*  qsb       = (bf16*)(ws + 54525952);         // 8 MB  [H][S][HD]
    bf16*  kbb       = (bf16*)(ws + 62914560);         // 2 MB  [4][S][HD]
    bf16*  vTb       = (bf16*)(ws + 65011712);         // 2 MB  [4][HD][S]
    float* out  = (float*)d_out;
    float* attn = out + 4194304;

    cvt4_kernel<<<dim3(4096), 256, 0, stream>>>(hidden, bf_hidden, 1048576);
    cvt4_kernel<<<dim3(4096), 256, 0, stream>>>(wq, bf_wqkv, 1048576);
    cvt4_kernel<<<dim3(1024), 256, 0, stream>>>(wk, bf_wqkv + 2048 * 2048, 262144);
    cvt4_kernel<<<dim3(1024), 256, 0, stream>>>(wv, bf_wqkv + 2048 * 2048 + 512 * 2048, 262144);
    cvt4_kernel<<<dim3(4096), 256, 0, stream>>>(wo, bf_wo, 1048576);

    // QKV projection: [2048 x 2048] @ [3072 x 2048]^T
    gemm128_bt<<<dim3(16, 24), 256, 0, stream>>>(bf_hidden, bf_wqkv, qkv_raw, NQKV, DM);

    rope_kernel<<<dim3(12, S), 256, 0, stream>>>(qkv_raw, cosb, sinb, qsb, kbb, vTb);

    attn_kernel<1><<<dim3(32, H), 1024, 0, stream>>>(qsb, kbb, attn, 0);
    attn_kernel<2><<<dim3(32, H), 1024, 0, stream>>>(qsb, kbb, attn, 32);
    attn_kernel<3><<<dim3(32, H), 1024, 0, stream>>>(qsb, kbb, attn, 64);
    attn_kernel<4><<<dim3(32, H), 1024, 0, stream>>>(qsb, kbb, attn, 96);

    av128<<<dim3(32, H), 256, 0, stream>>>(attn, vTb, bf_hidden);

    // out = o @ wo^T
    gemm128_bt<<<dim3(16, 16), 256, 0, stream>>>(bf_hidden, bf_wo, out, DM, DM);
}

// Round 3
// 689.164 us; speedup vs baseline: 1.9246x; 1.0069x over previous
//
#include <hip/hip_runtime.h>

typedef __bf16 bf16;
typedef __bf16 bf16x4 __attribute__((ext_vector_type(4)));
typedef __bf16 bf16x8 __attribute__((ext_vector_type(8)));
typedef float f32x4 __attribute__((ext_vector_type(4)));

#define S 2048
#define DM 2048
#define HD 128
#define H 16
#define NQKV 3072
#define N_ITER_DEV 32

__device__ __forceinline__ void gl2lds16(const void* g, void* l) {
    __builtin_amdgcn_global_load_lds(
        (const __attribute__((address_space(1))) void*)g,
        (__attribute__((address_space(3))) void*)l, 16, 0, 0);
}

// ---------------- fused fp32 -> bf16 convert for all 5 inputs ----------------
// f4 index space: hidden [0,1048576) | wq [1048576,2097152) | wk [...,2359296)
//                 | wv [...,2621440) | wo [...,3670016)
__global__ void cvt_all(const float* __restrict__ hid, const float* __restrict__ wq,
                        const float* __restrict__ wk, const float* __restrict__ wv,
                        const float* __restrict__ wo, bf16* __restrict__ bh,
                        bf16* __restrict__ bqkv, bf16* __restrict__ bwo) {
    int i = blockIdx.x * blockDim.x + threadIdx.x;
    const float* src;
    bf16* dst;
    int off;
    if (i < 1048576) { src = hid; dst = bh; off = i; }
    else if (i < 2097152) { src = wq; dst = bqkv; off = i - 1048576; }
    else if (i < 2359296) { src = wk; dst = bqkv + 2048 * 2048; off = i - 2097152; }
    else if (i < 2621440) { src = wv; dst = bqkv + 2048 * 2048 + 512 * 2048; off = i - 2359296; }
    else { src = wo; dst = bwo; off = i - 2621440; }
    float4 f = ((const float4*)src)[off];
    bf16x4 o;
    o[0] = (bf16)f.x; o[1] = (bf16)f.y; o[2] = (bf16)f.z; o[3] = (bf16)f.w;
    ((bf16x4*)dst)[off] = o;
}

// ---------------- 128x128-tile GEMM: C[m][n] = sum_k A[m][k]*B[n][k] ----------------
__global__ __launch_bounds__(256) void gemm128_bt(const bf16* __restrict__ A,
                                                  const bf16* __restrict__ B,
                                                  float* __restrict__ C, int Ndim, int K) {
    __shared__ bf16 As[128 * 32];
    __shared__ bf16 Bs[128 * 32];
    int m0 = blockIdx.x * 128, n0 = blockIdx.y * 128;
    int t = threadIdx.x;
    int l = t & 63, w = t >> 6;
    int lane16 = l & 15, quad = l >> 4;

    int c0 = (w * 2) * 64 + l;
    int c1 = c0 + 64;
    const bf16* Abase = A + (size_t)m0 * K;
    const bf16* Bbase = B + (size_t)n0 * K;

    int wm = (w & 1) * 64, wn = (w >> 1) * 64;
    f32x4 acc[4][4];
#pragma unroll
    for (int i = 0; i < 4; i++)
#pragma unroll
        for (int j = 0; j < 4; j++) acc[i][j] = (f32x4){0.f, 0.f, 0.f, 0.f};

    for (int k0 = 0; k0 < K; k0 += 32) {
        gl2lds16(Abase + (size_t)(c0 >> 2) * K + k0 + (c0 & 3) * 8, &As[(w * 2) * 512]);
        gl2lds16(Abase + (size_t)(c1 >> 2) * K + k0 + (c1 & 3) * 8, &As[(w * 2 + 1) * 512]);
        gl2lds16(Bbase + (size_t)(c0 >> 2) * K + k0 + (c0 & 3) * 8, &Bs[(w * 2) * 512]);
        gl2lds16(Bbase + (size_t)(c1 >> 2) * K + k0 + (c1 & 3) * 8, &Bs[(w * 2 + 1) * 512]);
        __syncthreads();
        bf16x8 af[4], bfr[4];
#pragma unroll
        for (int i = 0; i < 4; i++)
            af[i] = *(const bf16x8*)&As[(wm + i * 16 + lane16) * 32 + quad * 8];
#pragma unroll
        for (int j = 0; j < 4; j++)
            bfr[j] = *(const bf16x8*)&Bs[(wn + j * 16 + lane16) * 32 + quad * 8];
#pragma unroll
        for (int i = 0; i < 4; i++)
#pragma unroll
            for (int j = 0; j < 4; j++)
                acc[i][j] = __builtin_amdgcn_mfma_f32_16x16x32_bf16(af[i], bfr[j], acc[i][j], 0, 0, 0);
        __syncthreads();
    }
#pragma unroll
    for (int i = 0; i < 4; i++)
#pragma unroll
        for (int j = 0; j < 4; j++) {
            float* cp = C + (size_t)(m0 + wm + i * 16 + quad * 4) * Ndim + n0 + wn + j * 16 + lane16;
#pragma unroll
            for (int r = 0; r < 4; r++) cp[(size_t)r * Ndim] = acc[i][j][r];
        }
}

// ---------------- RoPE + reorder + scale-fold + bf16 ----------------
__global__ void rope_kernel(const float* __restrict__ qkv, const float* __restrict__ cosb,
                            const float* __restrict__ sinb, bf16* __restrict__ qs,
                            bf16* __restrict__ kb, bf16* __restrict__ vT) {
    int col = blockIdx.x * 256 + threadIdx.x;  // 0..3071
    int s = blockIdx.y;
    const float* row = qkv + (size_t)s * NQKV;
    float v = row[col];
    if (col < DM) {
        int h = col >> 7, d = col & 127;
        float c = cosb[s * HD + d], sn = sinb[s * HD + d];
        float other = row[(h << 7) + ((d < 64) ? (d + 64) : (d - 64))];
        float rot = (d < 64) ? -other : other;
        float o = v * c + rot * sn;
        qs[((size_t)h * S + s) * HD + d] = (bf16)(o * 0.04419417382415922f);  // HD^-0.5 * (alpha-1)
    } else if (col < DM + 512) {
        int c2 = col - DM;
        int kv = c2 >> 7, d = c2 & 127;
        float c = cosb[s * HD + d], sn = sinb[s * HD + d];
        float other = row[DM + (kv << 7) + ((d < 64) ? (d + 64) : (d - 64))];
        float rot = (d < 64) ? -other : other;
        float o = v * c + rot * sn;
        kb[((size_t)kv * S + s) * HD + d] = (bf16)o;
    } else {
        int c2 = col - DM - 512;
        int kv = c2 >> 7, d = c2 & 127;
        vT[((size_t)kv * HD + d) * S + s] = (bf16)v;
    }
}

// ------- fused: scores (MFMA) + causal mask + entmax bisection + attn write + P.V (MFMA) -------
// Block: 1024 thr = 16 waves, handles (head, 16 query rows). Wave w owns row r0+w for bisection.
// After tau known: per 512-col segment, p written to LDS bf16 + attn global, then MFMA vs vT.
template <int SEGS>
__global__ __launch_bounds__(1024) void attn_av_kernel(const bf16* __restrict__ qs,
                                                       const bf16* __restrict__ kb,
                                                       const bf16* __restrict__ vT,
                                                       float* __restrict__ attn,
                                                       bf16* __restrict__ o, int bx_base) {
    constexpr int NREG = SEGS * 8;
    __shared__ float sc[16][528];   // scores round-trip; reused for O cross-wave combine
    __shared__ bf16 pb[16][552];    // P (bf16) per segment; stride 552 -> 2-way banks (free)
    int bx = bx_base + blockIdx.x;
    int h = blockIdx.y;
    int r0 = bx * 16;
    int jlen = r0 + 16;
    int l = threadIdx.x & 63;
    int w = threadIdx.x >> 6;
    int lane16 = l & 15, quad = l >> 4;

    const bf16* qrow = qs + ((size_t)h * S + (r0 + lane16)) * HD + quad * 8;
    bf16x8 afrag[4];
#pragma unroll
    for (int kc = 0; kc < 4; kc++) afrag[kc] = *(const bf16x8*)(qrow + kc * 32);

    const bf16* kbase = kb + (size_t)(h >> 2) * S * HD;
    const bf16* vbase = vT + (size_t)(h >> 2) * HD * S;
    float xr[NREG];
    int my_i = r0 + w;

    // ---- scores into registers (row layout) ----
#pragma unroll
    for (int sgi = 0; sgi < SEGS; sgi++) {
        int j0 = sgi * 512;
#pragma unroll
        for (int tt = 0; tt < 2; tt++) {
            int t = w + tt * 16;
            int jt = j0 + t * 16;
            if (jt < jlen) {
                f32x4 acc = {0.f, 0.f, 0.f, 0.f};
                const bf16* kp = kbase + (size_t)(jt + lane16) * HD + quad * 8;
#pragma unroll
                for (int kc = 0; kc < 4; kc++) {
                    bf16x8 b = *(const bf16x8*)(kp + kc * 32);
                    acc = __builtin_amdgcn_mfma_f32_16x16x32_bf16(afrag[kc], b, acc, 0, 0, 0);
                }
                int jj = jt + lane16;
#pragma unroll
                for (int r = 0; r < 4; r++) {
                    int rowi = quad * 4 + r;
                    float v = acc[r];
                    if (jj > r0 + rowi) v = -1e30f;
                    sc[rowi][t * 16 + lane16] = v;
                }
            }
        }
        __syncthreads();
#pragma unroll
        for (int c = 0; c < 8; c++) {
            int j = j0 + c * 64 + l;
            xr[sgi * 8 + c] = (j < jlen) ? sc[w][c * 64 + l] : -1e30f;
        }
        __syncthreads();
    }

    // ---- entmax-1.5 bisection (wave w owns row my_i) ----
    float m = -1e30f;
#pragma unroll
    for (int c = 0; c < NREG; c++) m = fmaxf(m, xr[c]);
#pragma unroll
    for (int off = 1; off < 64; off <<= 1) m = fmaxf(m, __shfl_xor(m, off));

    float tau_lo = m - 1.0f;
    float dmh = 0.97790291309f;  // 1 - (1/2048)^0.5
    float tau_m = tau_lo;
    for (int it = 0; it < N_ITER_DEV; it++) {
        dmh *= 0.5f;
        tau_m = tau_lo + dmh;
        float f = 0.f;
#pragma unroll
        for (int c = 0; c < NREG; c++) {
            float t = fmaxf(xr[c] - tau_m, 0.f);
            f = fmaf(t, t, f);
        }
#pragma unroll
        for (int off = 1; off < 64; off <<= 1) f += __shfl_xor(f, off);
        tau_lo = (f >= 1.0f) ? tau_m : tau_lo;
    }

    float ssum = 0.f;
#pragma unroll
    for (int c = 0; c < NREG; c++) {
        float t = fmaxf(xr[c] - tau_m, 0.f);
        ssum = fmaf(t, t, ssum);
    }
#pragma unroll
    for (int off = 1; off < 64; off <<= 1) ssum += __shfl_xor(ssum, off);
    float inv = 1.0f / ssum;

    // ---- per segment: write attn (global fp32 + LDS bf16), then P.V MFMA ----
    float* arow = attn + ((size_t)h * S + my_i) * S;
    int jt_o = (w & 7) * 16;      // this wave's O col-tile
    int kh = (w >> 3) * 256;      // this wave's K half within segment
    f32x4 acc_o = {0.f, 0.f, 0.f, 0.f};

#pragma unroll
    for (int sgi = 0; sgi < SEGS; sgi++) {
        int j0 = sgi * 512;
#pragma unroll
        for (int c = 0; c < 8; c++) {
            float t = fmaxf(xr[sgi * 8 + c] - tau_m, 0.f);
            float p = t * t * inv;
            arow[j0 + c * 64 + l] = p;
            pb[w][c * 64 + l] = (bf16)p;
        }
        __syncthreads();
#pragma unroll
        for (int ks = 0; ks < 8; ks++) {
            int kk = kh + ks * 32;
            bf16x8 a = *(const bf16x8*)&pb[lane16][kk + quad * 8];
            bf16x8 b = *(const bf16x8*)(vbase + (size_t)(jt_o + lane16) * S + j0 + kk + quad * 8);
            acc_o = __builtin_amdgcn_mfma_f32_16x16x32_bf16(a, b, acc_o, 0, 0, 0);
        }
        __syncthreads();
    }

    // zeros for cols beyond this class's segment span
    for (int j = SEGS * 512 + l; j < S; j += 64) arow[j] = 0.f;

    // ---- combine K-halves (waves w>=8 -> LDS, waves w<8 add + write O) ----
    if (w >= 8) {
#pragma unroll
        for (int r = 0; r < 4; r++) sc[w - 8][l * 4 + r] = acc_o[r];
    }
    __syncthreads();
    if (w < 8) {
        bf16* op = o + (size_t)(r0 + quad * 4) * DM + h * HD + jt_o + lane16;
#pragma unroll
        for (int r = 0; r < 4; r++) {
            float v = acc_o[r] + sc[w][l * 4 + r];
            op[(size_t)r * DM] = (bf16)v;
        }
    }
}

extern "C" void kernel_launch(void* const* d_in, const int* in_sizes, int n_in,
                              void* d_out, int out_size, void* d_ws, size_t ws_size,
                              hipStream_t stream) {
    const float* hidden = (const float*)d_in[0];
    const float* cosb   = (const float*)d_in[1];
    const float* sinb   = (const float*)d_in[2];
    const float* wq     = (const float*)d_in[3];
    const float* wk     = (const float*)d_in[4];
    const float* wv     = (const float*)d_in[5];
    const float* wo     = (const float*)d_in[6];
    char* ws = (char*)d_ws;
    bf16*  bf_hidden = (bf16*)(ws);                    // 8 MB; reused as O bf16 later
    bf16*  bf_wqkv   = (bf16*)(ws + 8388608);          // 12 MB
    bf16*  bf_wo     = (bf16*)(ws + 20971520);         // 8 MB
    float* qkv_raw   = (float*)(ws + 29360128);        // 24 MB
    bf16*  qsb       = (bf16*)(ws + 54525952);         // 8 MB  [H][S][HD]
    bf16*  kbb       = (bf16*)(ws + 62914560);         // 2 MB  [4][S][HD]
    bf16*  vTb       = (bf16*)(ws + 65011712);         // 2 MB  [4][HD][S]
    float* out  = (float*)d_out;
    float* attn = out + 4194304;

    cvt_all<<<dim3(14336), 256, 0, stream>>>(hidden, wq, wk, wv, wo, bf_hidden, bf_wqkv, bf_wo);

    // QKV projection: [2048 x 2048] @ [3072 x 2048]^T
    gemm128_bt<<<dim3(16, 24), 256, 0, stream>>>(bf_hidden, bf_wqkv, qkv_raw, NQKV, DM);

    rope_kernel<<<dim3(12, S), 256, 0, stream>>>(qkv_raw, cosb, sinb, qsb, kbb, vTb);

    // fused scores + entmax + attn write + P.V  (O bf16 -> bf_hidden reuse)
    attn_av_kernel<1><<<dim3(32, H), 1024, 0, stream>>>(qsb, kbb, vTb, attn, bf_hidden, 0);
    attn_av_kernel<2><<<dim3(32, H), 1024, 0, stream>>>(qsb, kbb, vTb, attn, bf_hidden, 32);
    attn_av_kernel<3><<<dim3(32, H), 1024, 0, stream>>>(qsb, kbb, vTb, attn, bf_hidden, 64);
    attn_av_kernel<4><<<dim3(32, H), 1024, 0, stream>>>(qsb, kbb, vTb, attn, bf_hidden, 96);

    // out = O @ wo^T
    gemm128_bt<<<dim3(16, 16), 256, 0, stream>>>(bf_hidden, bf_wo, out, DM, DM);
}